// Round 9
// baseline (25.010 us; speedup 1.0000x reference)
//
#include <hip/hip_runtime.h>

#define EPSV 1e-4f
#define LOG2E 1.4426950408889634f

typedef float v4f __attribute__((ext_vector_type(4)));
typedef float v2f __attribute__((ext_vector_type(2)));

// out(i,j) of element = e0*g0i*g0j + e1*g1i*g1j + e2*g2i*g2j + eps*delta.
// K is compile-time -> indices fold; diag eps-add folds per-K.
#define VAL(K)                                                             \
  (fmaf(e0 * g0[(K) / 9], g0[(K) % 9],                                     \
        fmaf(e1 * g1[(K) / 9], g1[(K) % 9],                                \
             (e2 * g2[(K) / 9]) * g2[(K) % 9])) +                          \
   (((K) / 9 == (K) % 9) ? EPSV : 0.0f))

// Fast cyclic-Jacobi rotation (validated rounds 7-8: absmax 0.25).
__device__ __forceinline__ void jrot(float& app, float& aqq, float& apq,
                                     float& arp, float& arq,
                                     float& vap, float& vaq,
                                     float& vbp, float& vbq,
                                     float& vcp, float& vcq) {
  const float apq0 = apq;
  const float tau = (aqq - app) * (0.5f * __builtin_amdgcn_rcpf(apq0));
  float t = copysignf(
      __builtin_amdgcn_rcpf(fabsf(tau) + sqrtf(fmaf(tau, tau, 1.0f))), tau);
  if (apq0 == 0.0f) t = 0.0f;
  const float c = __builtin_amdgcn_rsqf(fmaf(t, t, 1.0f));
  const float s = t * c;
  const float d = t * apq0;
  app -= d; aqq += d; apq = 0.0f;
  float x, y;
  x = arp; y = arq; arp = fmaf(c, x, -(s * y)); arq = fmaf(s, x, c * y);
  x = vap; y = vaq; vap = fmaf(c, x, -(s * y)); vaq = fmaf(s, x, c * y);
  x = vbp; y = vbq; vbp = fmaf(c, x, -(s * y)); vbq = fmaf(s, x, c * y);
  x = vcp; y = vcq; vcp = fmaf(c, x, -(s * y)); vcq = fmaf(s, x, c * y);
}

// Round-6 skeleton + two changes:
// (1) staging via 40 ds_write_b64 + 1 ds_write_b32 per element (parity-
//     aligned pair packing) instead of 81 scalar writes: LDS-pipe instrs
//     per wave 345 -> ~185.
// (2) phase rotation h = (hh + w + blockIdx) & 3: decoheres the wave convoy
//     so one wave's LDS-staging overlaps another's HBM drain.
__global__ __launch_bounds__(256, 4) void spd_decoder_kernel(
    const float* __restrict__ vech, const float* __restrict__ W1,
    const float* __restrict__ W2, const float* __restrict__ W3,
    float* __restrict__ out, int B) {
  __shared__ float Tsh[21];                      // W2@W1 (7x3)
  __shared__ float Msh[27];                      // W3@W2@W1 (9x3)
  __shared__ __align__(16) float buf[4][1296];   // per-wave staging (16*81)

  const int tid = threadIdx.x;

  // ---- issue input loads first (hide fetch latency under M precompute) ----
  const int e = blockIdx.x * 256 + tid;     // B is a multiple of 256
  const float2* vp = reinterpret_cast<const float2*>(vech + (size_t)e * 6);
  const float2 p0 = vp[0], p1 = vp[1], p2 = vp[2];

  // ---- per-block precompute of M = W3@W2@W1 ----
  if (tid < 21) {
    const int r = tid / 3, c = tid % 3;
    float acc = 0.f;
#pragma unroll
    for (int j = 0; j < 5; ++j) acc += W2[r * 5 + j] * W1[j * 3 + c];
    Tsh[tid] = acc;
  }
  __syncthreads();
  if (tid < 27) {
    const int r = tid / 3, c = tid % 3;
    float acc = 0.f;
#pragma unroll
    for (int j = 0; j < 7; ++j) acc += W3[r * 7 + j] * Tsh[j * 3 + c];
    Msh[tid] = acc;
  }
  __syncthreads();

  float a00 = p0.x, a01 = p0.y, a02 = p1.x, a11 = p1.y, a12 = p2.x, a22 = p2.y;

  // ---- 3x3 Jacobi, 4 sweeps (validated), V accumulated ----
  float v00 = 1.f, v01 = 0.f, v02 = 0.f;
  float v10 = 0.f, v11 = 1.f, v12 = 0.f;
  float v20 = 0.f, v21 = 0.f, v22 = 1.f;
#pragma unroll
  for (int sweep = 0; sweep < 4; ++sweep) {
    jrot(a00, a11, a01, a02, a12, v00, v01, v10, v11, v20, v21);  // (0,1)
    jrot(a00, a22, a02, a01, a12, v00, v02, v10, v12, v20, v22);  // (0,2)
    jrot(a11, a22, a12, a01, a02, v01, v02, v11, v12, v21, v22);  // (1,2)
  }

  const float e0 = exp2f(a00 * LOG2E) - EPSV;
  const float e1 = exp2f(a11 * LOG2E) - EPSV;
  const float e2 = exp2f(a22 * LOG2E) - EPSV;

  // ---- g_k = M v_k ----
  float g0[9], g1[9], g2[9];
#pragma unroll
  for (int i = 0; i < 9; ++i) {
    const float m0 = Msh[i * 3 + 0], m1 = Msh[i * 3 + 1], m2 = Msh[i * 3 + 2];
    g0[i] = fmaf(m0, v00, fmaf(m1, v10, m2 * v20));
    g1[i] = fmaf(m0, v01, fmaf(m1, v11, m2 * v21));
    g2[i] = fmaf(m0, v02, fmaf(m1, v12, m2 * v22));
  }

  const int w = tid >> 6, l = tid & 63;
  float* wbuf = &buf[w][0];
  const size_t base = (size_t)(blockIdx.x * 256 + w * 64) * 81;
  const int rot = (w + blockIdx.x) & 3;   // convoy decoherence

#pragma unroll
  for (int hh = 0; hh < 4; ++hh) {
    const int h = (hh + rot) & 3;        // this wave's phase order, rotated
    if ((l >> 4) == h) {                 // quarter-wave writer group
      const int ll = l & 15;
      const int d = ll & 1;              // slot byte base 324*ll: %8 = 4*d
      float* dst = wbuf + ll * 81;       // word stride 81: <=2-way banks
      // parity-shifted pair packing: even lanes write (v2t,v2t+1) at dst+2t,
      // odd lanes (v2t+1,v2t+2) at dst+1+2t; scalar v80 (even) / v0 (odd).
      v2f* pdst = reinterpret_cast<v2f*>(dst + d);  // 8B-aligned for all ll
      const float v0 = VAL(0);
      float carry = v0;
#pragma unroll
      for (int t = 0; t < 40; ++t) {
        const float vA = VAL(2 * t + 1);
        const float vB = VAL(2 * t + 2);
        v2f pv;
        pv.x = d ? vA : carry;
        pv.y = d ? vB : vA;
        pdst[t] = pv;                    // ds_write_b64 (mergeable to write2)
        carry = vB;
      }
      dst[d ? 0 : 80] = d ? v0 : carry;  // the one unpaired float
    }
    // cross-lane RAW: this phase's writes land before any lane reads them.
    asm volatile("s_waitcnt lgkmcnt(0)" ::: "memory");

    // 1296 contiguous floats = 324 float4, nontemporal (write-once stream)
    const size_t sb = base + (size_t)h * 1296;
    const v4f* rbuf = reinterpret_cast<const v4f*>(wbuf);
    v4f* outv = reinterpret_cast<v4f*>(out + sb);
#pragma unroll
    for (int it = 0; it < 5; ++it)
      __builtin_nontemporal_store(rbuf[it * 64 + l], outv + it * 64 + l);
    if (l < 4) __builtin_nontemporal_store(rbuf[320 + l], outv + 320 + l);
  }
}

extern "C" void kernel_launch(void* const* d_in, const int* in_sizes, int n_in,
                              void* d_out, int out_size, void* d_ws, size_t ws_size,
                              hipStream_t stream) {
  const float* vech = (const float*)d_in[0];
  const float* W1 = (const float*)d_in[1];
  const float* W2 = (const float*)d_in[2];
  const float* W3 = (const float*)d_in[3];
  float* out = (float*)d_out;
  const int B = in_sizes[0] / 6;  // 262144
  dim3 grid(B / 256), block(256);
  hipLaunchKernelGGL(spd_decoder_kernel, grid, block, 0, stream,
                     vech, W1, W2, W3, out, B);
}

// Round 10
// 24.313 us; speedup vs baseline: 1.0287x; 1.0287x over previous
//
#include <hip/hip_runtime.h>

#define EPSV 1e-4f

// One cyclic-Jacobi rotation for the symmetric 3x3, pair (p,q), other index r.
__device__ __forceinline__ void jrot(float& app, float& aqq, float& apq,
                                     float& arp, float& arq,
                                     float& vap, float& vaq,
                                     float& vbp, float& vbq,
                                     float& vcp, float& vcq) {
  const float apq0 = apq;
  float tau = (aqq - app) / (2.0f * apq0);               // may be inf/nan if apq0==0
  float t = copysignf(1.0f / (fabsf(tau) + sqrtf(fmaf(tau, tau, 1.0f))), tau);
  if (apq0 == 0.0f) t = 0.0f;                            // covers the nan case too
  const float c = rsqrtf(fmaf(t, t, 1.0f));
  const float s = t * c;
  const float d = t * apq0;
  app -= d; aqq += d; apq = 0.0f;
  const float rp = arp, rq = arq;
  arp = c * rp - s * rq;
  arq = s * rp + c * rq;
  float x, y;
  x = vap; y = vaq; vap = c * x - s * y; vaq = s * x + c * y;
  x = vbp; y = vbq; vbp = c * x - s * y; vbq = s * x + c * y;
  x = vcp; y = vcq; vcp = c * x - s * y; vcq = s * x + c * y;
}

// Reverted to the round-3 artifact: empirically fastest (24.348us; the 24.35
// class reproduced across two independent rounds). Six orthogonal structural
// interventions since (sync structure x3, nt-stores, b64 staging, phase
// rotation, occupancy 7-28 waves/CU, compute +-40%) were all null at the
// 24.4us floor, consistent with {~13.5us HBM store floor + ~2us kernel-side
// residue + ~8-9us fixed launch/replay overhead in the reported metric}.
__global__ __launch_bounds__(256, 2) void spd_decoder_kernel(
    const float* __restrict__ vech, const float* __restrict__ W1,
    const float* __restrict__ W2, const float* __restrict__ W3,
    float* __restrict__ out, int B) {
  __shared__ float Tsh[21];                 // W2@W1 (7x3)
  __shared__ float Msh[27];                 // W3@W2@W1 (9x3)
  __shared__ __align__(16) float buf[4][2592];  // per-wave staging (32 elem * 81)

  const int tid = threadIdx.x;

  // ---- per-block precompute of M = W3@W2@W1 ----
  if (tid < 21) {
    const int r = tid / 3, c = tid % 3;
    float acc = 0.f;
#pragma unroll
    for (int j = 0; j < 5; ++j) acc += W2[r * 5 + j] * W1[j * 3 + c];
    Tsh[tid] = acc;
  }
  __syncthreads();
  if (tid < 27) {
    const int r = tid / 3, c = tid % 3;
    float acc = 0.f;
#pragma unroll
    for (int j = 0; j < 7; ++j) acc += W3[r * 7 + j] * Tsh[j * 3 + c];
    Msh[tid] = acc;
  }
  __syncthreads();

  // ---- load vech, build symmetric 3x3 ----
  const int e = blockIdx.x * 256 + tid;     // B is a multiple of 256
  const float2* vp = reinterpret_cast<const float2*>(vech + (size_t)e * 6);
  const float2 p0 = vp[0], p1 = vp[1], p2 = vp[2];
  float a00 = p0.x, a01 = p0.y, a02 = p1.x, a11 = p1.y, a12 = p2.x, a22 = p2.y;

  // ---- 3x3 Jacobi eigendecomposition, V accumulated ----
  float v00 = 1.f, v01 = 0.f, v02 = 0.f;
  float v10 = 0.f, v11 = 1.f, v12 = 0.f;
  float v20 = 0.f, v21 = 0.f, v22 = 1.f;
#pragma unroll
  for (int sweep = 0; sweep < 5; ++sweep) {
    jrot(a00, a11, a01, a02, a12, v00, v01, v10, v11, v20, v21);  // (0,1), r=2
    jrot(a00, a22, a02, a01, a12, v00, v02, v10, v12, v20, v22);  // (0,2), r=1
    jrot(a11, a22, a12, a01, a02, v01, v02, v11, v12, v21, v22);  // (1,2), r=0
  }

  const float e0 = expf(a00) - EPSV;
  const float e1 = expf(a11) - EPSV;
  const float e2 = expf(a22) - EPSV;

  // ---- g_k = M v_k (9 floats each); output values generated on the fly:
  // out[i][j] = e0 g0i g0j + e1 g1i g1j + e2 g2i g2j + eps*delta_ij. ----
  float g0[9], g1[9], g2[9];
#pragma unroll
  for (int i = 0; i < 9; ++i) {
    const float m0 = Msh[i * 3 + 0], m1 = Msh[i * 3 + 1], m2 = Msh[i * 3 + 2];
    g0[i] = fmaf(m0, v00, fmaf(m1, v10, m2 * v20));
    g1[i] = fmaf(m0, v01, fmaf(m1, v11, m2 * v21));
    g2[i] = fmaf(m0, v02, fmaf(m1, v12, m2 * v22));
  }

  // ---- wave-private staged store, two phases of 32 elements, no block
  // barrier and no vmcnt drain: each wave only touches buf[w]; DS ops
  // complete in order within a wave, so wave-local lgkmcnt(0) covers the
  // cross-lane RAW (write->read) and WAR (read->next write) hazards while
  // global stores stay in flight across phases and waves. ----
  const int w = tid >> 6, l = tid & 63;
  float* wbuf = &buf[w][0];
  const size_t base = (size_t)(blockIdx.x * 256 + w * 64) * 81;

#pragma unroll
  for (int h = 0; h < 2; ++h) {
    if ((l >> 5) == h) {
      const int ll = l & 31;
      float* dst = wbuf + ll * 81;  // stride 81 (mod 32 = 17): conflict-free
#pragma unroll
      for (int i = 0; i < 9; ++i) {
        const float t0 = e0 * g0[i], t1 = e1 * g1[i], t2 = e2 * g2[i];
#pragma unroll
        for (int j = 0; j < 9; ++j) {
          float val = fmaf(t0, g0[j], fmaf(t1, g1[j], t2 * g2[j]));
          if (i == j) val += EPSV;     // compile-time branch after unroll
          dst[i * 9 + j] = val;
        }
      }
    }
    // writes landed before any lane's reads (wave-local wait, no vmcnt)
    asm volatile("s_waitcnt lgkmcnt(0)" ::: "memory");
    __builtin_amdgcn_sched_barrier(0);

    const size_t sb = base + (size_t)h * 2592;
    const float4* rbuf = reinterpret_cast<const float4*>(wbuf);
    float4* outv = reinterpret_cast<float4*>(out + sb);
#pragma unroll
    for (int it = 0; it < 10; ++it) outv[it * 64 + l] = rbuf[it * 64 + l];
    if (l < 8) outv[640 + l] = rbuf[640 + l];  // 648 float4 total

    // reads landed (data in VGPRs) before next phase overwrites the buffer
    asm volatile("s_waitcnt lgkmcnt(0)" ::: "memory");
    __builtin_amdgcn_sched_barrier(0);
  }
}

extern "C" void kernel_launch(void* const* d_in, const int* in_sizes, int n_in,
                              void* d_out, int out_size, void* d_ws, size_t ws_size,
                              hipStream_t stream) {
  const float* vech = (const float*)d_in[0];
  const float* W1 = (const float*)d_in[1];
  const float* W2 = (const float*)d_in[2];
  const float* W3 = (const float*)d_in[3];
  float* out = (float*)d_out;
  const int B = in_sizes[0] / 6;  // 262144
  dim3 grid(B / 256), block(256);
  hipLaunchKernelGGL(spd_decoder_kernel, grid, block, 0, stream,
                     vech, W1, W2, W3, out, B);
}

// Round 11
// 24.264 us; speedup vs baseline: 1.0308x; 1.0020x over previous
//
#include <hip/hip_runtime.h>

#define EPSV 1e-4f

// One cyclic-Jacobi rotation for the symmetric 3x3, pair (p,q), other index r.
__device__ __forceinline__ void jrot(float& app, float& aqq, float& apq,
                                     float& arp, float& arq,
                                     float& vap, float& vaq,
                                     float& vbp, float& vbq,
                                     float& vcp, float& vcq) {
  const float apq0 = apq;
  float tau = (aqq - app) / (2.0f * apq0);               // may be inf/nan if apq0==0
  float t = copysignf(1.0f / (fabsf(tau) + sqrtf(fmaf(tau, tau, 1.0f))), tau);
  if (apq0 == 0.0f) t = 0.0f;                            // covers the nan case too
  const float c = rsqrtf(fmaf(t, t, 1.0f));
  const float s = t * c;
  const float d = t * apq0;
  app -= d; aqq += d; apq = 0.0f;
  const float rp = arp, rq = arq;
  arp = c * rp - s * rq;
  arq = s * rp + c * rq;
  float x, y;
  x = vap; y = vaq; vap = c * x - s * y; vaq = s * x + c * y;
  x = vbp; y = vbq; vbp = c * x - s * y; vbq = s * x + c * y;
  x = vcp; y = vcq; vcp = c * x - s * y; vcq = s * x + c * y;
}

// Reverted to the round-3 artifact: empirically fastest (24.348us; the 24.35
// class reproduced across two independent rounds). Six orthogonal structural
// interventions since (sync structure x3, nt-stores, b64 staging, phase
// rotation, occupancy 7-28 waves/CU, compute +-40%) were all null at the
// 24.4us floor, consistent with {~13.5us HBM store floor + ~2us kernel-side
// residue + ~8-9us fixed launch/replay overhead in the reported metric}.
__global__ __launch_bounds__(256, 2) void spd_decoder_kernel(
    const float* __restrict__ vech, const float* __restrict__ W1,
    const float* __restrict__ W2, const float* __restrict__ W3,
    float* __restrict__ out, int B) {
  __shared__ float Tsh[21];                 // W2@W1 (7x3)
  __shared__ float Msh[27];                 // W3@W2@W1 (9x3)
  __shared__ __align__(16) float buf[4][2592];  // per-wave staging (32 elem * 81)

  const int tid = threadIdx.x;

  // ---- per-block precompute of M = W3@W2@W1 ----
  if (tid < 21) {
    const int r = tid / 3, c = tid % 3;
    float acc = 0.f;
#pragma unroll
    for (int j = 0; j < 5; ++j) acc += W2[r * 5 + j] * W1[j * 3 + c];
    Tsh[tid] = acc;
  }
  __syncthreads();
  if (tid < 27) {
    const int r = tid / 3, c = tid % 3;
    float acc = 0.f;
#pragma unroll
    for (int j = 0; j < 7; ++j) acc += W3[r * 7 + j] * Tsh[j * 3 + c];
    Msh[tid] = acc;
  }
  __syncthreads();

  // ---- load vech, build symmetric 3x3 ----
  const int e = blockIdx.x * 256 + tid;     // B is a multiple of 256
  const float2* vp = reinterpret_cast<const float2*>(vech + (size_t)e * 6);
  const float2 p0 = vp[0], p1 = vp[1], p2 = vp[2];
  float a00 = p0.x, a01 = p0.y, a02 = p1.x, a11 = p1.y, a12 = p2.x, a22 = p2.y;

  // ---- 3x3 Jacobi eigendecomposition, V accumulated ----
  float v00 = 1.f, v01 = 0.f, v02 = 0.f;
  float v10 = 0.f, v11 = 1.f, v12 = 0.f;
  float v20 = 0.f, v21 = 0.f, v22 = 1.f;
#pragma unroll
  for (int sweep = 0; sweep < 5; ++sweep) {
    jrot(a00, a11, a01, a02, a12, v00, v01, v10, v11, v20, v21);  // (0,1), r=2
    jrot(a00, a22, a02, a01, a12, v00, v02, v10, v12, v20, v22);  // (0,2), r=1
    jrot(a11, a22, a12, a01, a02, v01, v02, v11, v12, v21, v22);  // (1,2), r=0
  }

  const float e0 = expf(a00) - EPSV;
  const float e1 = expf(a11) - EPSV;
  const float e2 = expf(a22) - EPSV;

  // ---- g_k = M v_k (9 floats each); output values generated on the fly:
  // out[i][j] = e0 g0i g0j + e1 g1i g1j + e2 g2i g2j + eps*delta_ij. ----
  float g0[9], g1[9], g2[9];
#pragma unroll
  for (int i = 0; i < 9; ++i) {
    const float m0 = Msh[i * 3 + 0], m1 = Msh[i * 3 + 1], m2 = Msh[i * 3 + 2];
    g0[i] = fmaf(m0, v00, fmaf(m1, v10, m2 * v20));
    g1[i] = fmaf(m0, v01, fmaf(m1, v11, m2 * v21));
    g2[i] = fmaf(m0, v02, fmaf(m1, v12, m2 * v22));
  }

  // ---- wave-private staged store, two phases of 32 elements, no block
  // barrier and no vmcnt drain: each wave only touches buf[w]; DS ops
  // complete in order within a wave, so wave-local lgkmcnt(0) covers the
  // cross-lane RAW (write->read) and WAR (read->next write) hazards while
  // global stores stay in flight across phases and waves. ----
  const int w = tid >> 6, l = tid & 63;
  float* wbuf = &buf[w][0];
  const size_t base = (size_t)(blockIdx.x * 256 + w * 64) * 81;

#pragma unroll
  for (int h = 0; h < 2; ++h) {
    if ((l >> 5) == h) {
      const int ll = l & 31;
      float* dst = wbuf + ll * 81;  // stride 81 (mod 32 = 17): conflict-free
#pragma unroll
      for (int i = 0; i < 9; ++i) {
        const float t0 = e0 * g0[i], t1 = e1 * g1[i], t2 = e2 * g2[i];
#pragma unroll
        for (int j = 0; j < 9; ++j) {
          float val = fmaf(t0, g0[j], fmaf(t1, g1[j], t2 * g2[j]));
          if (i == j) val += EPSV;     // compile-time branch after unroll
          dst[i * 9 + j] = val;
        }
      }
    }
    // writes landed before any lane's reads (wave-local wait, no vmcnt)
    asm volatile("s_waitcnt lgkmcnt(0)" ::: "memory");
    __builtin_amdgcn_sched_barrier(0);

    const size_t sb = base + (size_t)h * 2592;
    const float4* rbuf = reinterpret_cast<const float4*>(wbuf);
    float4* outv = reinterpret_cast<float4*>(out + sb);
#pragma unroll
    for (int it = 0; it < 10; ++it) outv[it * 64 + l] = rbuf[it * 64 + l];
    if (l < 8) outv[640 + l] = rbuf[640 + l];  // 648 float4 total

    // reads landed (data in VGPRs) before next phase overwrites the buffer
    asm volatile("s_waitcnt lgkmcnt(0)" ::: "memory");
    __builtin_amdgcn_sched_barrier(0);
  }
}

extern "C" void kernel_launch(void* const* d_in, const int* in_sizes, int n_in,
                              void* d_out, int out_size, void* d_ws, size_t ws_size,
                              hipStream_t stream) {
  const float* vech = (const float*)d_in[0];
  const float* W1 = (const float*)d_in[1];
  const float* W2 = (const float*)d_in[2];
  const float* W3 = (const float*)d_in[3];
  float* out = (float*)d_out;
  const int B = in_sizes[0] / 6;  // 262144
  dim3 grid(B / 256), block(256);
  hipLaunchKernelGGL(spd_decoder_kernel, grid, block, 0, stream,
                     vech, W1, W2, W3, out, B);
}